// Round 9
// baseline (274.229 us; speedup 1.0000x reference)
//
#include <hip/hip_runtime.h>
#include <math.h>

#define HDIM 128
#define BSH 9                 // bucket shift: 512 nodes per bucket
#define CH 4096               // edges per binning chunk
#define GEMM_BLKS 256         // gemm blocks inside each fused kernel
#define GSPLIT 352            // gemm row-groups done in F2; rest in F3

typedef __attribute__((ext_vector_type(8))) short short8;
typedef __attribute__((ext_vector_type(4))) float f32x4;

__device__ inline unsigned short bf16_hi(float f) {
    return (unsigned short)(__float_as_uint(f) >> 16);
}
__device__ inline unsigned short bf16_rn(float f) {
    unsigned int u = __float_as_uint(f);
    return (unsigned short)((u + 0x7FFF + ((u >> 16) & 1)) >> 16);
}

// ---------- 1. bucket histogram + fused scan (last-done-block) ----------
__global__ __launch_bounds__(256) void binA_kernel(
    const int* __restrict__ dst, int E, int* __restrict__ bcnt,
    int* __restrict__ done, int* __restrict__ bbase, int* __restrict__ bcur,
    int* __restrict__ row_ptr, int NB, int n, int nblocks) {
    __shared__ int hist[256];
    __shared__ int lastflag;
    const int t = threadIdx.x;
    const int c0 = blockIdx.x * CH;
    hist[t] = 0;
    __syncthreads();
    #pragma unroll
    for (int k = 0; k < CH / 256; ++k) {
        int e = c0 + t + (k << 8);
        if (e < E) atomicAdd(&hist[dst[e] >> BSH], 1);
    }
    __syncthreads();
    if (hist[t] > 0) atomicAdd(&bcnt[t], hist[t]);
    __threadfence();
    if (t == 0) {
        int old = atomicAdd(done, 1);
        lastflag = (old == nblocks - 1) ? 1 : 0;
    }
    __syncthreads();
    if (!lastflag) return;
    int v = (t < NB) ? atomicAdd(&bcnt[t], 0) : 0;
    hist[t] = v;
    __syncthreads();
    for (int off = 1; off < 256; off <<= 1) {
        int u = (t >= off) ? hist[t - off] : 0;
        __syncthreads();
        hist[t] += u;
        __syncthreads();
    }
    int excl = hist[t] - v;
    if (t < NB) { bbase[t] = excl; bcur[t] = excl; }
    if (t == 0) { bbase[NB] = E; row_ptr[n] = E; }
}

// ---------- gemm device body: gb[row][col] = bf16(x @ W^T), split-bf16 MFMA ----------
__device__ __forceinline__ void gemm_body(
    const float* __restrict__ x, const float* __restrict__ W,
    unsigned short* __restrict__ gb, int n,
    int g0, int g1, int bid, int nblk, char* smem_raw) {
    uint4* Wh = (uint4*)smem_raw;          // 32 KB
    uint4* Wl = ((uint4*)smem_raw) + 2048; // 32 KB

    const int t = threadIdx.x;
    const int wave = t >> 6;
    const int lane = t & 63;
    const int q = lane >> 4;
    const int m = lane & 15;

    for (int idx = t; idx < 2048; idx += 256) {
        const int j = idx >> 4;
        const int c = idx & 15;
        const float4* wp = (const float4*)(W + (size_t)j * HDIM + c * 8);
        float4 va = wp[0], vb = wp[1];
        float vs[8] = {va.x, va.y, va.z, va.w, vb.x, vb.y, vb.z, vb.w};
        unsigned short h[8], l[8];
        #pragma unroll
        for (int k = 0; k < 8; ++k) {
            h[k] = bf16_hi(vs[k]);
            float hf = __uint_as_float((unsigned int)h[k] << 16);
            l[k] = bf16_hi(vs[k] - hf);
        }
        uint4 hch, lch;
        hch.x = (unsigned int)h[0] | ((unsigned int)h[1] << 16);
        hch.y = (unsigned int)h[2] | ((unsigned int)h[3] << 16);
        hch.z = (unsigned int)h[4] | ((unsigned int)h[5] << 16);
        hch.w = (unsigned int)h[6] | ((unsigned int)h[7] << 16);
        lch.x = (unsigned int)l[0] | ((unsigned int)l[1] << 16);
        lch.y = (unsigned int)l[2] | ((unsigned int)l[3] << 16);
        lch.z = (unsigned int)l[4] | ((unsigned int)l[5] << 16);
        lch.w = (unsigned int)l[6] | ((unsigned int)l[7] << 16);
        const int sidx = (j << 4) | (c ^ (j & 15));
        Wh[sidx] = hch;
        Wl[sidx] = lch;
    }
    __syncthreads();

    for (int grp = g0 + bid; grp < g1; grp += nblk) {
        const int rowbase = (grp << 7) + (wave << 5);

        f32x4 acc[2][8];
        #pragma unroll
        for (int mt = 0; mt < 2; ++mt)
            #pragma unroll
            for (int ct = 0; ct < 8; ++ct)
                acc[mt][ct] = (f32x4){0.f, 0.f, 0.f, 0.f};

        #pragma unroll
        for (int kk = 0; kk < 4; ++kk) {
            short8 ah[2], al[2];
            #pragma unroll
            for (int mt = 0; mt < 2; ++mt) {
                const int r = rowbase + (mt << 4) + m;
                float vs[8];
                if (r < n) {
                    const float4* xp = (const float4*)(x + (size_t)r * HDIM + (kk << 5) + (q << 3));
                    float4 va = xp[0], vb = xp[1];
                    vs[0] = va.x; vs[1] = va.y; vs[2] = va.z; vs[3] = va.w;
                    vs[4] = vb.x; vs[5] = vb.y; vs[6] = vb.z; vs[7] = vb.w;
                } else {
                    #pragma unroll
                    for (int k = 0; k < 8; ++k) vs[k] = 0.f;
                }
                #pragma unroll
                for (int k = 0; k < 8; ++k) {
                    unsigned short h = bf16_hi(vs[k]);
                    float hf = __uint_as_float((unsigned int)h << 16);
                    unsigned short lo = bf16_hi(vs[k] - hf);
                    ah[mt][k] = (short)h;
                    al[mt][k] = (short)lo;
                }
            }
            #pragma unroll
            for (int ct = 0; ct < 8; ++ct) {
                const int nn = (ct << 4) + m;
                const int sidx = (nn << 4) | (((kk << 2) + q) ^ m);
                short8 bh = *(const short8*)&Wh[sidx];
                short8 bl = *(const short8*)&Wl[sidx];
                #pragma unroll
                for (int mt = 0; mt < 2; ++mt) {
                    acc[mt][ct] = __builtin_amdgcn_mfma_f32_16x16x32_bf16(ah[mt], bh, acc[mt][ct], 0, 0, 0);
                    acc[mt][ct] = __builtin_amdgcn_mfma_f32_16x16x32_bf16(al[mt], bh, acc[mt][ct], 0, 0, 0);
                    acc[mt][ct] = __builtin_amdgcn_mfma_f32_16x16x32_bf16(ah[mt], bl, acc[mt][ct], 0, 0, 0);
                }
            }
        }

        #pragma unroll
        for (int mt = 0; mt < 2; ++mt) {
            #pragma unroll
            for (int rr = 0; rr < 4; ++rr) {
                const int grow = rowbase + (mt << 4) + (q << 2) + rr;
                if (grow < n) {
                    unsigned short* gp = gb + (size_t)grow * HDIM + m;
                    #pragma unroll
                    for (int ct = 0; ct < 8; ++ct)
                        gp[ct << 4] = bf16_rn(acc[mt][ct][rr]);
                }
            }
        }
    }
}

// ---------- binB device body (round-7 simple form) ----------
__device__ __forceinline__ void binB_body(
    const int* __restrict__ ei, int E,
    int* __restrict__ bcur, unsigned int* __restrict__ eb,
    int chunk, char* smem_raw) {
    int* hist = (int*)smem_raw;
    int* base = hist + 256;
    int* cur  = base + 256;
    const int t = threadIdx.x;
    const int c0 = chunk * CH;
    hist[t] = 0;
    __syncthreads();

    int sv[CH / 256], dv[CH / 256];
    #pragma unroll
    for (int k = 0; k < CH / 256; ++k) {
        int e = c0 + t + (k << 8);
        if (e < E) {
            sv[k] = ei[e];
            dv[k] = ei[E + e];
            atomicAdd(&hist[dv[k] >> BSH], 1);
        } else {
            dv[k] = -1;
        }
    }
    __syncthreads();
    if (hist[t] > 0) base[t] = atomicAdd(&bcur[t], hist[t]);
    cur[t] = 0;
    __syncthreads();
    #pragma unroll
    for (int k = 0; k < CH / 256; ++k) {
        if (dv[k] >= 0) {
            int bkt = dv[k] >> BSH;
            int o = atomicAdd(&cur[bkt], 1);
            eb[(size_t)base[bkt] + o] =
                ((unsigned int)(dv[k] & ((1 << BSH) - 1)) << 23) | (unsigned int)sv[k];
        }
    }
}

// ---------- binC device body (256 threads, pair-owned 512-node bucket) ----------
__device__ __forceinline__ void binC_body(
    const unsigned int* __restrict__ eb, const int* __restrict__ bbase,
    int* __restrict__ row_ptr, float* __restrict__ dinv,
    int* __restrict__ col, int n, int b, char* smem_raw) {
    int* hist = (int*)smem_raw;        // 512
    int* cur  = hist + 512;            // 512
    int* wsum = cur + 512;             // 4
    const int t = threadIdx.x;
    const int node0 = b << BSH;
    const int e0 = bbase[b];
    const int e1 = bbase[b + 1];

    hist[t] = 0; hist[t + 256] = 0;
    __syncthreads();
    for (int e = e0 + t; e < e1; e += 256)
        atomicAdd(&hist[eb[e] >> 23], 1);
    __syncthreads();
    const int v0 = hist[2 * t];
    const int v1 = hist[2 * t + 1];
    const int pt = v0 + v1;
    int xp = pt;
    #pragma unroll
    for (int off = 1; off < 64; off <<= 1) {
        int u = __shfl_up(xp, off);
        if ((t & 63) >= off) xp += u;
    }
    if ((t & 63) == 63) wsum[t >> 6] = xp;
    __syncthreads();
    if (t < 4) {
        int y = wsum[t];
        #pragma unroll
        for (int off = 1; off < 4; off <<= 1) {
            int u = __shfl_up(y, off);
            if (t >= off) y += u;
        }
        wsum[t] = y;
    }
    __syncthreads();
    const int px = xp - pt + ((t >> 6) ? wsum[(t >> 6) - 1] : 0);
    const int c0 = e0 + px, c1 = e0 + px + v0;
    cur[2 * t] = c0;
    cur[2 * t + 1] = c1;
    int node = node0 + 2 * t;
    if (node < n)     { row_ptr[node] = c0;     dinv[node] = rsqrtf((float)v0 + 1.0f); }
    if (node + 1 < n) { row_ptr[node + 1] = c1; dinv[node + 1] = rsqrtf((float)v1 + 1.0f); }
    __syncthreads();
    for (int e = e0 + t; e < e1; e += 256) {
        unsigned int p = eb[e];
        int pos = atomicAdd(&cur[p >> 23], 1);
        col[pos] = (int)(p & 0x7FFFFF);
    }
}

// ---------- F2: binB (blocks 0..nchunk) || gemm part A ----------
__global__ __launch_bounds__(256) void fuseB_kernel(
    const int* __restrict__ ei, int E, int* __restrict__ bcur,
    unsigned int* __restrict__ eb,
    const float* __restrict__ x, const float* __restrict__ W,
    unsigned short* __restrict__ gb, int n, int nchunk) {
    __shared__ __attribute__((aligned(16))) char smem[65536];
    const int bid = blockIdx.x;
    if (bid < nchunk)
        binB_body(ei, E, bcur, eb, bid, smem);
    else
        gemm_body(x, W, gb, n, 0, GSPLIT, bid - nchunk, GEMM_BLKS, smem);
}

// ---------- F3: binC (blocks 0..NB) || gemm part B ----------
__global__ __launch_bounds__(256) void fuseC_kernel(
    const unsigned int* __restrict__ eb, const int* __restrict__ bbase,
    int* __restrict__ row_ptr, float* __restrict__ dinv, int* __restrict__ col,
    const float* __restrict__ x, const float* __restrict__ W,
    unsigned short* __restrict__ gb, int n, int NB, int ngroups) {
    __shared__ __attribute__((aligned(16))) char smem[65536];
    const int bid = blockIdx.x;
    if (bid < NB)
        binC_body(eb, bbase, row_ptr, dinv, col, n, bid, smem);
    else
        gemm_body(x, W, gb, n, GSPLIT, ngroups, bid - NB, GEMM_BLKS, smem);
}

// ---------- gather: quarter-wave per edge, 16B/lane, dinv[src] applied per edge ----------
__global__ __launch_bounds__(256) void gather_kernel(
    const int* __restrict__ row_ptr, const int* __restrict__ col,
    const uint4* __restrict__ gbr, const float* __restrict__ dinv,
    const float* __restrict__ bias, const float* __restrict__ prelu_a,
    float* __restrict__ out, int n) {
    const int wv = threadIdx.x >> 6;
    const int lane = threadIdx.x & 63;
    const int q = lane >> 4;
    const int l16 = lane & 15;
    const int i = blockIdx.x * 4 + wv;
    if (i >= n) return;

    const int beg = row_ptr[i];
    const int end = row_ptr[i + 1];
    const float di = dinv[i];

    float a[8];
    #pragma unroll
    for (int k = 0; k < 8; ++k) a[k] = 0.f;

    if (q == 0) {   // self term: dinv_i * h_i
        uint4 u = gbr[(size_t)i * 16 + l16];
        a[0] = fmaf(di, __uint_as_float(u.x << 16), a[0]);
        a[1] = fmaf(di, __uint_as_float(u.x & 0xffff0000u), a[1]);
        a[2] = fmaf(di, __uint_as_float(u.y << 16), a[2]);
        a[3] = fmaf(di, __uint_as_float(u.y & 0xffff0000u), a[3]);
        a[4] = fmaf(di, __uint_as_float(u.z << 16), a[4]);
        a[5] = fmaf(di, __uint_as_float(u.z & 0xffff0000u), a[5]);
        a[6] = fmaf(di, __uint_as_float(u.w << 16), a[6]);
        a[7] = fmaf(di, __uint_as_float(u.w & 0xffff0000u), a[7]);
    }

    int e = beg + q;
    for (; e + 4 < end; e += 8) {
        int s0 = col[e];
        int s1 = col[e + 4];
        float d0 = dinv[s0];
        float d1 = dinv[s1];
        uint4 u0 = gbr[(size_t)s0 * 16 + l16];
        uint4 u1 = gbr[(size_t)s1 * 16 + l16];
        a[0] = fmaf(d0, __uint_as_float(u0.x << 16), a[0]);
        a[1] = fmaf(d0, __uint_as_float(u0.x & 0xffff0000u), a[1]);
        a[2] = fmaf(d0, __uint_as_float(u0.y << 16), a[2]);
        a[3] = fmaf(d0, __uint_as_float(u0.y & 0xffff0000u), a[3]);
        a[4] = fmaf(d0, __uint_as_float(u0.z << 16), a[4]);
        a[5] = fmaf(d0, __uint_as_float(u0.z & 0xffff0000u), a[5]);
        a[6] = fmaf(d0, __uint_as_float(u0.w << 16), a[6]);
        a[7] = fmaf(d0, __uint_as_float(u0.w & 0xffff0000u), a[7]);
        a[0] = fmaf(d1, __uint_as_float(u1.x << 16), a[0]);
        a[1] = fmaf(d1, __uint_as_float(u1.x & 0xffff0000u), a[1]);
        a[2] = fmaf(d1, __uint_as_float(u1.y << 16), a[2]);
        a[3] = fmaf(d1, __uint_as_float(u1.y & 0xffff0000u), a[3]);
        a[4] = fmaf(d1, __uint_as_float(u1.z << 16), a[4]);
        a[5] = fmaf(d1, __uint_as_float(u1.z & 0xffff0000u), a[5]);
        a[6] = fmaf(d1, __uint_as_float(u1.w << 16), a[6]);
        a[7] = fmaf(d1, __uint_as_float(u1.w & 0xffff0000u), a[7]);
    }
    if (e < end) {
        int s = col[e];
        float d = dinv[s];
        uint4 u = gbr[(size_t)s * 16 + l16];
        a[0] = fmaf(d, __uint_as_float(u.x << 16), a[0]);
        a[1] = fmaf(d, __uint_as_float(u.x & 0xffff0000u), a[1]);
        a[2] = fmaf(d, __uint_as_float(u.y << 16), a[2]);
        a[3] = fmaf(d, __uint_as_float(u.y & 0xffff0000u), a[3]);
        a[4] = fmaf(d, __uint_as_float(u.z << 16), a[4]);
        a[5] = fmaf(d, __uint_as_float(u.z & 0xffff0000u), a[5]);
        a[6] = fmaf(d, __uint_as_float(u.w << 16), a[6]);
        a[7] = fmaf(d, __uint_as_float(u.w & 0xffff0000u), a[7]);
    }

    #pragma unroll
    for (int k = 0; k < 8; ++k) {
        a[k] += __shfl_xor(a[k], 16);
        a[k] += __shfl_xor(a[k], 32);
    }

    const float aa = prelu_a[0];
    const int c0 = (l16 << 3) + (q << 1);
    float2 bb = *(const float2*)(bias + c0);
    float v0 = di * a[(q << 1) + 0] + bb.x;
    float v1 = di * a[(q << 1) + 1] + bb.y;
    v0 = v0 >= 0.f ? v0 : aa * v0;
    v1 = v1 >= 0.f ? v1 : aa * v1;
    *(float2*)(out + (size_t)i * HDIM + c0) = make_float2(v0, v1);
}

extern "C" void kernel_launch(void* const* d_in, const int* in_sizes, int n_in,
                              void* d_out, int out_size, void* d_ws, size_t ws_size,
                              hipStream_t stream) {
    const float* x  = (const float*)d_in[0];
    const int*   ei = (const int*)d_in[1];   // edge_index (2, E), int32
    const float* W  = (const float*)d_in[2];
    const float* b  = (const float*)d_in[3];
    const float* pa = (const float*)d_in[4];

    const int n = in_sizes[0] / HDIM;        // 100000
    const int E = in_sizes[1] / 2;           // 1600000
    const int NB = (n + (1 << BSH) - 1) >> BSH;   // 196 buckets
    const int ngroups = (n + 127) >> 7;      // 782 gemm row-groups

    float* out = (float*)d_out;

    // workspace layout (16B-aligned first):
    //   gb      : n*128 ushort    (25.6 MB, row-major)
    //   eb      : E uint          (6.4 MB, packed ldst|src)
    //   dinv    : n floats
    //   row_ptr : n+1 ints
    //   col     : E ints
    //   bcnt[256] | done[1] | bbase[257] | bcur[256]
    unsigned short* gb      = (unsigned short*)d_ws;
    unsigned int*   eb      = (unsigned int*)(gb + (size_t)n * HDIM);
    float*          dinv    = (float*)(eb + (size_t)E);
    int*            row_ptr = (int*)(dinv + n);
    int*            col     = row_ptr + (n + 1);
    int*            bcnt    = col + E;
    int*            done    = bcnt + 256;
    int*            bbase   = done + 1;
    int*            bcur    = bbase + 257;

    hipMemsetAsync(bcnt, 0, 257 * sizeof(int), stream);   // bcnt + done

    const int nchunk = (E + CH - 1) / CH;    // 391
    binA_kernel<<<nchunk, 256, 0, stream>>>(ei + E, E, bcnt, done, bbase, bcur,
                                            row_ptr, NB, n, nchunk);
    fuseB_kernel<<<nchunk + GEMM_BLKS, 256, 0, stream>>>(ei, E, bcur, eb, x, W, gb, n, nchunk);
    fuseC_kernel<<<NB + GEMM_BLKS, 256, 0, stream>>>(eb, bbase, row_ptr, dinv, col,
                                                     x, W, gb, n, NB, ngroups);
    gather_kernel<<<(n + 3) / 4, 256, 0, stream>>>(row_ptr, col, (const uint4*)gb,
                                                   dinv, b, pa, out, n);
}

// Round 10
// 255.547 us; speedup vs baseline: 1.0731x; 1.0731x over previous
//
#include <hip/hip_runtime.h>
#include <math.h>

#define HDIM 128
#define BSH 9                 // bucket shift: 512 nodes per bucket
#define CH 4096               // edges per binning chunk
#define GEMM_BLKS 256         // gemm blocks inside each fused kernel
#define GSPLIT 160            // gemm row-groups in fuse1 (binA); rest in fuse2 (binB)

typedef __attribute__((ext_vector_type(8))) short short8;
typedef __attribute__((ext_vector_type(4))) float f32x4;

__device__ inline unsigned short bf16_hi(float f) {
    return (unsigned short)(__float_as_uint(f) >> 16);
}
__device__ inline unsigned short bf16_rn(float f) {
    unsigned int u = __float_as_uint(f);
    return (unsigned short)((u + 0x7FFF + ((u >> 16) & 1)) >> 16);
}

// ---------- 0. prep: W (fp32) -> Whg/Wlg (bf16 hi + residual lo, global) ----------
__global__ __launch_bounds__(256) void prep_kernel(
    const float* __restrict__ W, uint4* __restrict__ Whg, uint4* __restrict__ Wlg) {
    const int t = threadIdx.x;
    for (int idx = t; idx < 2048; idx += 256) {
        const int j = idx >> 4;
        const int c = idx & 15;
        const float4* wp = (const float4*)(W + (size_t)j * HDIM + c * 8);
        float4 va = wp[0], vb = wp[1];
        float vs[8] = {va.x, va.y, va.z, va.w, vb.x, vb.y, vb.z, vb.w};
        unsigned short h[8], l[8];
        #pragma unroll
        for (int k = 0; k < 8; ++k) {
            h[k] = bf16_hi(vs[k]);
            float hf = __uint_as_float((unsigned int)h[k] << 16);
            l[k] = bf16_hi(vs[k] - hf);
        }
        uint4 hch, lch;
        hch.x = (unsigned int)h[0] | ((unsigned int)h[1] << 16);
        hch.y = (unsigned int)h[2] | ((unsigned int)h[3] << 16);
        hch.z = (unsigned int)h[4] | ((unsigned int)h[5] << 16);
        hch.w = (unsigned int)h[6] | ((unsigned int)h[7] << 16);
        lch.x = (unsigned int)l[0] | ((unsigned int)l[1] << 16);
        lch.y = (unsigned int)l[2] | ((unsigned int)l[3] << 16);
        lch.z = (unsigned int)l[4] | ((unsigned int)l[5] << 16);
        lch.w = (unsigned int)l[6] | ((unsigned int)l[7] << 16);
        Whg[idx] = hch;
        Wlg[idx] = lch;
    }
}

// ---------- gemm body (LDS-free): gb[row][col] = bf16(x @ W^T) ----------
__device__ __forceinline__ void gemm_body(
    const float* __restrict__ x, const uint4* __restrict__ Whg,
    const uint4* __restrict__ Wlg, unsigned short* __restrict__ gb, int n,
    int g0, int g1, int bid, int nblk) {
    const int t = threadIdx.x;
    const int wave = t >> 6;
    const int lane = t & 63;
    const int q = lane >> 4;
    const int m = lane & 15;

    for (int grp = g0 + bid; grp < g1; grp += nblk) {
        const int rowbase = (grp << 7) + (wave << 5);

        f32x4 acc[2][8];
        #pragma unroll
        for (int mt = 0; mt < 2; ++mt)
            #pragma unroll
            for (int ct = 0; ct < 8; ++ct)
                acc[mt][ct] = (f32x4){0.f, 0.f, 0.f, 0.f};

        #pragma unroll
        for (int kk = 0; kk < 4; ++kk) {
            short8 ah[2], al[2];
            #pragma unroll
            for (int mt = 0; mt < 2; ++mt) {
                const int r = rowbase + (mt << 4) + m;
                float vs[8];
                if (r < n) {
                    const float4* xp = (const float4*)(x + (size_t)r * HDIM + (kk << 5) + (q << 3));
                    float4 va = xp[0], vb = xp[1];
                    vs[0] = va.x; vs[1] = va.y; vs[2] = va.z; vs[3] = va.w;
                    vs[4] = vb.x; vs[5] = vb.y; vs[6] = vb.z; vs[7] = vb.w;
                } else {
                    #pragma unroll
                    for (int k = 0; k < 8; ++k) vs[k] = 0.f;
                }
                #pragma unroll
                for (int k = 0; k < 8; ++k) {
                    unsigned short h = bf16_hi(vs[k]);
                    float hf = __uint_as_float((unsigned int)h << 16);
                    unsigned short lo = bf16_hi(vs[k] - hf);
                    ah[mt][k] = (short)h;
                    al[mt][k] = (short)lo;
                }
            }
            #pragma unroll
            for (int ct = 0; ct < 8; ++ct) {
                const int nn = (ct << 4) + m;
                const int fidx = (nn << 4) | ((kk << 2) + q);
                short8 bh = *(const short8*)&Whg[fidx];
                short8 bl = *(const short8*)&Wlg[fidx];
                #pragma unroll
                for (int mt = 0; mt < 2; ++mt) {
                    acc[mt][ct] = __builtin_amdgcn_mfma_f32_16x16x32_bf16(ah[mt], bh, acc[mt][ct], 0, 0, 0);
                    acc[mt][ct] = __builtin_amdgcn_mfma_f32_16x16x32_bf16(al[mt], bh, acc[mt][ct], 0, 0, 0);
                    acc[mt][ct] = __builtin_amdgcn_mfma_f32_16x16x32_bf16(ah[mt], bl, acc[mt][ct], 0, 0, 0);
                }
            }
        }

        #pragma unroll
        for (int mt = 0; mt < 2; ++mt) {
            #pragma unroll
            for (int rr = 0; rr < 4; ++rr) {
                const int grow = rowbase + (mt << 4) + (q << 2) + rr;
                if (grow < n) {
                    unsigned short* gp = gb + (size_t)grow * HDIM + m;
                    #pragma unroll
                    for (int ct = 0; ct < 8; ++ct)
                        gp[ct << 4] = bf16_rn(acc[mt][ct][rr]);
                }
            }
        }
    }
}

// ---------- binA body: bucket histogram ----------
__device__ __forceinline__ void binA_body(
    const int* __restrict__ dst, int E, int* __restrict__ bcnt,
    int chunk, int* hist) {
    const int t = threadIdx.x;
    const int c0 = chunk * CH;
    hist[t] = 0;
    __syncthreads();
    #pragma unroll
    for (int k = 0; k < CH / 256; ++k) {
        int e = c0 + t + (k << 8);
        if (e < E) atomicAdd(&hist[dst[e] >> BSH], 1);
    }
    __syncthreads();
    if (hist[t] > 0) atomicAdd(&bcnt[t], hist[t]);
}

// ---------- binB body (round-7 simple): bin edges to bucket-major eb ----------
__device__ __forceinline__ void binB_body(
    const int* __restrict__ ei, int E,
    int* __restrict__ bcur, unsigned int* __restrict__ eb,
    int chunk, int* hist, int* base, int* cur) {
    const int t = threadIdx.x;
    const int c0 = chunk * CH;
    hist[t] = 0;
    __syncthreads();

    int sv[CH / 256], dv[CH / 256];
    #pragma unroll
    for (int k = 0; k < CH / 256; ++k) {
        int e = c0 + t + (k << 8);
        if (e < E) {
            sv[k] = ei[e];
            dv[k] = ei[E + e];
            atomicAdd(&hist[dv[k] >> BSH], 1);
        } else {
            dv[k] = -1;
        }
    }
    __syncthreads();
    if (hist[t] > 0) base[t] = atomicAdd(&bcur[t], hist[t]);
    cur[t] = 0;
    __syncthreads();
    #pragma unroll
    for (int k = 0; k < CH / 256; ++k) {
        if (dv[k] >= 0) {
            int bkt = dv[k] >> BSH;
            int o = atomicAdd(&cur[bkt], 1);
            eb[(size_t)base[bkt] + o] =
                ((unsigned int)(dv[k] & ((1 << BSH) - 1)) << 23) | (unsigned int)sv[k];
        }
    }
}

// ---------- fuse1: binA || gemm part A ----------
__global__ __launch_bounds__(256) void fuse1_kernel(
    const int* __restrict__ dst, int E, int* __restrict__ bcnt,
    const float* __restrict__ x, const uint4* __restrict__ Whg,
    const uint4* __restrict__ Wlg, unsigned short* __restrict__ gb,
    int n, int nchunk) {
    __shared__ int s_a[256];
    const int bid = blockIdx.x;
    if (bid < GEMM_BLKS)
        gemm_body(x, Whg, Wlg, gb, n, 0, GSPLIT, bid, GEMM_BLKS);
    else
        binA_body(dst, E, bcnt, bid - GEMM_BLKS, s_a);
}

// ---------- scanB: bucket counts -> bbase/bcur ----------
__global__ __launch_bounds__(256) void scanB_kernel(
    const int* __restrict__ bcnt, int* __restrict__ bbase, int* __restrict__ bcur,
    int NB, int E) {
    __shared__ int s[256];
    const int t = threadIdx.x;
    int v = (t < NB) ? bcnt[t] : 0;
    s[t] = v;
    __syncthreads();
    for (int off = 1; off < 256; off <<= 1) {
        int u = (t >= off) ? s[t - off] : 0;
        __syncthreads();
        s[t] += u;
        __syncthreads();
    }
    int excl = s[t] - v;
    if (t < NB) { bbase[t] = excl; bcur[t] = excl; }
    if (t == 0) bbase[NB] = E;
}

// ---------- fuse2: binB || gemm part B ----------
__global__ __launch_bounds__(256) void fuse2_kernel(
    const int* __restrict__ ei, int E, int* __restrict__ bcur,
    unsigned int* __restrict__ eb,
    const float* __restrict__ x, const uint4* __restrict__ Whg,
    const uint4* __restrict__ Wlg, unsigned short* __restrict__ gb,
    int n, int nchunk, int ngroups) {
    __shared__ int s_a[256], s_b[256], s_c[256];
    const int bid = blockIdx.x;
    if (bid < GEMM_BLKS)
        gemm_body(x, Whg, Wlg, gb, n, GSPLIT, ngroups, bid, GEMM_BLKS);
    else
        binB_body(ei, E, bcur, eb, bid - GEMM_BLKS, s_a, s_b, s_c);
}

// ---------- binC: per-bucket hist + shfl scan -> row_ptr/dinv, CSR fill ----------
__global__ __launch_bounds__(512) void binC_kernel(
    const unsigned int* __restrict__ eb, const int* __restrict__ bbase,
    int* __restrict__ row_ptr, float* __restrict__ dinv,
    int* __restrict__ col, int n) {
    __shared__ int hist[512];
    __shared__ int cur[512];
    __shared__ int wsum[8];
    const int t = threadIdx.x;
    const int b = blockIdx.x;
    const int node0 = b << BSH;
    const int e0 = bbase[b];
    const int e1 = bbase[b + 1];

    hist[t] = 0;
    __syncthreads();
    for (int e = e0 + t; e < e1; e += 512)
        atomicAdd(&hist[eb[e] >> 23], 1);
    __syncthreads();
    const int v = hist[t];
    int x = v;
    #pragma unroll
    for (int off = 1; off < 64; off <<= 1) {
        int u = __shfl_up(x, off);
        if ((t & 63) >= off) x += u;
    }
    if ((t & 63) == 63) wsum[t >> 6] = x;
    __syncthreads();
    if (t < 8) {
        int y = wsum[t];
        #pragma unroll
        for (int off = 1; off < 8; off <<= 1) {
            int u = __shfl_up(y, off);
            if (t >= off) y += u;
        }
        wsum[t] = y;
    }
    __syncthreads();
    int excl = x - v + ((t >> 6) ? wsum[(t >> 6) - 1] : 0);

    int node = node0 + t;
    if (node < n) {
        row_ptr[node] = e0 + excl;
        dinv[node] = rsqrtf((float)v + 1.0f);
        if (node == n - 1) row_ptr[n] = e0 + excl + v;
    }
    cur[t] = e0 + excl;
    __syncthreads();
    for (int e = e0 + t; e < e1; e += 512) {
        unsigned int p = eb[e];
        int pos = atomicAdd(&cur[p >> 23], 1);
        col[pos] = (int)(p & 0x7FFFFF);
    }
}

// ---------- gather: quarter-wave per edge, 16B/lane, 4-deep unroll ----------
#define EDGE_ACC(d, u) \
    a[0] = fmaf(d, __uint_as_float((u).x << 16), a[0]); \
    a[1] = fmaf(d, __uint_as_float((u).x & 0xffff0000u), a[1]); \
    a[2] = fmaf(d, __uint_as_float((u).y << 16), a[2]); \
    a[3] = fmaf(d, __uint_as_float((u).y & 0xffff0000u), a[3]); \
    a[4] = fmaf(d, __uint_as_float((u).z << 16), a[4]); \
    a[5] = fmaf(d, __uint_as_float((u).z & 0xffff0000u), a[5]); \
    a[6] = fmaf(d, __uint_as_float((u).w << 16), a[6]); \
    a[7] = fmaf(d, __uint_as_float((u).w & 0xffff0000u), a[7]);

__global__ __launch_bounds__(256) void gather_kernel(
    const int* __restrict__ row_ptr, const int* __restrict__ col,
    const uint4* __restrict__ gbr, const float* __restrict__ dinv,
    const float* __restrict__ bias, const float* __restrict__ prelu_a,
    float* __restrict__ out, int n) {
    const int wv = threadIdx.x >> 6;
    const int lane = threadIdx.x & 63;
    const int q = lane >> 4;
    const int l16 = lane & 15;
    const int i = blockIdx.x * 4 + wv;
    if (i >= n) return;

    const int beg = row_ptr[i];
    const int end = row_ptr[i + 1];
    const float di = dinv[i];

    float a[8];
    #pragma unroll
    for (int k = 0; k < 8; ++k) a[k] = 0.f;

    if (q == 0) {   // self term: dinv_i * h_i
        uint4 u = gbr[(size_t)i * 16 + l16];
        EDGE_ACC(di, u)
    }

    int e = beg + q;
    for (; e + 12 < end; e += 16) {        // 4 edges per quarter per iter
        int s0 = col[e];
        int s1 = col[e + 4];
        int s2 = col[e + 8];
        int s3 = col[e + 12];
        float d0 = dinv[s0], d1 = dinv[s1], d2 = dinv[s2], d3 = dinv[s3];
        uint4 u0 = gbr[(size_t)s0 * 16 + l16];
        uint4 u1 = gbr[(size_t)s1 * 16 + l16];
        uint4 u2 = gbr[(size_t)s2 * 16 + l16];
        uint4 u3 = gbr[(size_t)s3 * 16 + l16];
        EDGE_ACC(d0, u0)
        EDGE_ACC(d1, u1)
        EDGE_ACC(d2, u2)
        EDGE_ACC(d3, u3)
    }
    for (; e + 4 < end; e += 8) {          // 2 edges
        int s0 = col[e];
        int s1 = col[e + 4];
        float d0 = dinv[s0], d1 = dinv[s1];
        uint4 u0 = gbr[(size_t)s0 * 16 + l16];
        uint4 u1 = gbr[(size_t)s1 * 16 + l16];
        EDGE_ACC(d0, u0)
        EDGE_ACC(d1, u1)
    }
    if (e < end) {
        int s = col[e];
        float d = dinv[s];
        uint4 u = gbr[(size_t)s * 16 + l16];
        EDGE_ACC(d, u)
    }

    #pragma unroll
    for (int k = 0; k < 8; ++k) {
        a[k] += __shfl_xor(a[k], 16);
        a[k] += __shfl_xor(a[k], 32);
    }

    const float aa = prelu_a[0];
    const int c0 = (l16 << 3) + (q << 1);
    float2 bb = *(const float2*)(bias + c0);
    float v0 = di * a[(q << 1) + 0] + bb.x;
    float v1 = di * a[(q << 1) + 1] + bb.y;
    v0 = v0 >= 0.f ? v0 : aa * v0;
    v1 = v1 >= 0.f ? v1 : aa * v1;
    *(float2*)(out + (size_t)i * HDIM + c0) = make_float2(v0, v1);
}

extern "C" void kernel_launch(void* const* d_in, const int* in_sizes, int n_in,
                              void* d_out, int out_size, void* d_ws, size_t ws_size,
                              hipStream_t stream) {
    const float* x  = (const float*)d_in[0];
    const int*   ei = (const int*)d_in[1];   // edge_index (2, E), int32
    const float* W  = (const float*)d_in[2];
    const float* b  = (const float*)d_in[3];
    const float* pa = (const float*)d_in[4];

    const int n = in_sizes[0] / HDIM;        // 100000
    const int E = in_sizes[1] / 2;           // 1600000
    const int NB = (n + (1 << BSH) - 1) >> BSH;   // 196 buckets
    const int ngroups = (n + 127) >> 7;      // 782 gemm row-groups

    float* out = (float*)d_out;

    // workspace layout (16B-aligned first):
    //   gb   : n*128 ushort (25.6 MB) | eb : E uint (6.4 MB)
    //   Whg  : 2048 uint4 (32 KB)     | Wlg : 2048 uint4 (32 KB)
    //   dinv : n floats | row_ptr : n+1 | col : E | bcnt[256] bbase[257] bcur[256]
    unsigned short* gb      = (unsigned short*)d_ws;
    unsigned int*   eb      = (unsigned int*)(gb + (size_t)n * HDIM);
    uint4*          Whg     = (uint4*)(eb + (size_t)E);
    uint4*          Wlg     = Whg + 2048;
    float*          dinv    = (float*)(Wlg + 2048);
    int*            row_ptr = (int*)(dinv + n);
    int*            col     = row_ptr + (n + 1);
    int*            bcnt    = col + E;
    int*            bbase   = bcnt + 256;
    int*            bcur    = bbase + 257;

    hipMemsetAsync(bcnt, 0, 256 * sizeof(int), stream);

    const int nchunk = (E + CH - 1) / CH;    // 391
    prep_kernel<<<1, 256, 0, stream>>>(W, Whg, Wlg);
    fuse1_kernel<<<GEMM_BLKS + nchunk, 256, 0, stream>>>(ei + E, E, bcnt, x, Whg, Wlg, gb, n, nchunk);
    scanB_kernel<<<1, 256, 0, stream>>>(bcnt, bbase, bcur, NB, E);
    fuse2_kernel<<<GEMM_BLKS + nchunk, 256, 0, stream>>>(ei, E, bcur, eb, x, Whg, Wlg, gb, n, nchunk, ngroups);
    binC_kernel<<<NB, 512, 0, stream>>>(eb, bbase, row_ptr, dinv, col, n);
    gather_kernel<<<(n + 3) / 4, 256, 0, stream>>>(row_ptr, col, (const uint4*)gb, dinv, b, pa, out, n);
}